// Round 1
// baseline (1138.973 us; speedup 1.0000x reference)
//
#include <hip/hip_runtime.h>
#include <hip/hip_bf16.h>
#include <stdint.h>

// Problem constants (from reference): B=4, T=2048 -> N=8192 tokens
#define N_TOK 8192
#define C_DIM 1024
#define E_NUM 8
#define H_DIM 4096
#define ROWS_PAD 9216   // 8192 + 8*128 upper bound on per-expert 128-padded rows

typedef __attribute__((ext_vector_type(8))) short bf16x8;
typedef __attribute__((ext_vector_type(4))) float f32x4;

// round-to-nearest-even fp32 -> bf16
static __device__ __forceinline__ unsigned short f2bf(float f) {
    union { float f; unsigned u; } v; v.f = f;
    unsigned r = (v.u + 0x7FFFu + ((v.u >> 16) & 1u)) >> 16;
    return (unsigned short)r;
}

// async global->LDS, 16B per lane (LDS dest = wave-uniform base + lane*16)
static __device__ __forceinline__ void load_lds16(const unsigned short* g, unsigned short* l) {
    __builtin_amdgcn_global_load_lds(
        (const __attribute__((address_space(1))) unsigned int*)g,
        (__attribute__((address_space(3))) unsigned int*)l, 16, 0, 0);
}

// ---------------------------------------------------------------------------
// Transpose + cast: in [E][K][N] fp32  ->  out [E][N][K] bf16
// Reads coalesced (lanes = consecutive n); each lane writes its own 16B run.
// ---------------------------------------------------------------------------
__global__ void transpose_w(const float* __restrict__ in, unsigned short* __restrict__ out,
                            int K, int N) {
    int e  = blockIdx.z;
    int n0 = blockIdx.x * 64;
    int k0 = blockIdx.y * 256;
    int t = threadIdx.x;
    int lane = t & 63;
    int w = t >> 6;
    const float* ip = in + (size_t)e * K * N;
    unsigned short* op = out + (size_t)e * N * K;
    int n = n0 + lane;
    for (int kb = k0 + w * 8; kb < k0 + 256; kb += 32) {
        float v[8];
#pragma unroll
        for (int j = 0; j < 8; j++) v[j] = ip[(size_t)(kb + j) * N + n];
        uint4 pk;
        pk.x = (unsigned)f2bf(v[0]) | ((unsigned)f2bf(v[1]) << 16);
        pk.y = (unsigned)f2bf(v[2]) | ((unsigned)f2bf(v[3]) << 16);
        pk.z = (unsigned)f2bf(v[4]) | ((unsigned)f2bf(v[5]) << 16);
        pk.w = (unsigned)f2bf(v[6]) | ((unsigned)f2bf(v[7]) << 16);
        *(uint4*)&op[(size_t)n * K + kb] = pk;
    }
}

// ---------------------------------------------------------------------------
// Router: one wave per token. fp64 accumulation so our argmax matches the
// reference's fp32 result except for true near-ties.
// ---------------------------------------------------------------------------
__global__ void router_kernel(const float* __restrict__ x, const float* __restrict__ Wr,
                              const float* __restrict__ br,
                              float* __restrict__ probs, int* __restrict__ eidx,
                              int* __restrict__ cnt) {
    int n = blockIdx.x * 4 + (threadIdx.x >> 6);
    int lane = threadIdx.x & 63;
    const float* xr = x + (size_t)n * C_DIM;
    double acc[E_NUM];
#pragma unroll
    for (int e = 0; e < E_NUM; e++) acc[e] = 0.0;
    for (int i = 0; i < 16; i++) {
        int c = i * 64 + lane;
        float xv = xr[c];
        const float4* wr = (const float4*)(Wr + c * E_NUM);
        float4 w0 = wr[0], w1 = wr[1];
        acc[0] += (double)xv * w0.x; acc[1] += (double)xv * w0.y;
        acc[2] += (double)xv * w0.z; acc[3] += (double)xv * w0.w;
        acc[4] += (double)xv * w1.x; acc[5] += (double)xv * w1.y;
        acc[6] += (double)xv * w1.z; acc[7] += (double)xv * w1.w;
    }
#pragma unroll
    for (int e = 0; e < E_NUM; e++) {
#pragma unroll
        for (int o = 32; o > 0; o >>= 1) acc[e] += __shfl_xor(acc[e], o, 64);
    }
    if (lane == 0) {
        float l[E_NUM];
        for (int e = 0; e < E_NUM; e++) l[e] = (float)acc[e] + br[e];
        int arg = 0; float m = l[0];
        for (int e = 1; e < E_NUM; e++) if (l[e] > m) { m = l[e]; arg = e; }  // first-max
        float s = 0.f;
        for (int e = 0; e < E_NUM; e++) s += expf(l[e] - m);
        probs[n] = 1.0f / s;     // = exp(lmax-m)/sum
        eidx[n] = arg;
        atomicAdd(&cnt[arg], 1);
    }
}

// ---------------------------------------------------------------------------
// Finalize: 128-padded segment offsets + aux load-balance loss
// ---------------------------------------------------------------------------
__global__ void finalize_kernel(const int* __restrict__ cnt, int* __restrict__ seg,
                                float* __restrict__ aux_out) {
    if (threadIdx.x == 0) {
        int off = 0;
        for (int e = 0; e < E_NUM; e++) {
            seg[e] = off;
            off += ((cnt[e] + 127) >> 7) << 7;
        }
        float s = 0.f;
        for (int e = 0; e < E_NUM; e++) {
            float fr = (float)cnt[e] / (float)N_TOK - 1.0f / E_NUM;
            s += fr * fr;
        }
        aux_out[0] = s / (float)E_NUM;
    }
}

// ---------------------------------------------------------------------------
// Gather: expert-grouped bf16 copy of x; one wave per token
// ---------------------------------------------------------------------------
__global__ void gather_kernel(const float* __restrict__ x, const float* __restrict__ probs,
                              const int* __restrict__ eidx, const int* __restrict__ seg,
                              int* __restrict__ fill, unsigned short* __restrict__ xg,
                              int* __restrict__ inv_row, float* __restrict__ rowprob) {
    int n = blockIdx.x * 4 + (threadIdx.x >> 6);
    int lane = threadIdx.x & 63;
    int e = eidx[n];
    int pos = 0;
    if (lane == 0) pos = atomicAdd(&fill[e], 1);
    pos = __shfl(pos, 0, 64);
    int row = seg[e] + pos;
    if (lane == 0) { inv_row[row] = n; rowprob[row] = probs[n]; }
    const float2* xr = (const float2*)(x + (size_t)n * C_DIM);
    unsigned* xgr = (unsigned*)(xg + (size_t)row * C_DIM);
#pragma unroll
    for (int i = 0; i < 8; i++) {
        float2 v = xr[i * 64 + lane];
        xgr[i * 64 + lane] = (unsigned)f2bf(v.x) | ((unsigned)f2bf(v.y) << 16);
    }
}

// ---------------------------------------------------------------------------
// Grouped GEMM, m97 structure: 128x128 tile, BK=32, 256 thr (4 waves, each
// 64x64 = 4x4 MFMA 16x16x32 tiles). A [rows,K] bf16 k-contig, Bt [E][N][K]
// bf16 k-contig. EPI=1: +bias, exact gelu, bf16 store to hg.
// EPI=2: +bias, *gate, scatter fp32 to out by inv_row.
// ---------------------------------------------------------------------------
template <int KDIM, int NDIM, int EPI>
__global__ __launch_bounds__(256) void moe_gemm(
    const unsigned short* __restrict__ Ag, const unsigned short* __restrict__ Bt,
    const float* __restrict__ bias, unsigned short* __restrict__ hg,
    float* __restrict__ out, const int* __restrict__ cnt, const int* __restrict__ seg,
    const int* __restrict__ inv_row, const float* __restrict__ rowprob) {
    // map m-slot -> (expert, m-tile)
    int mt = blockIdx.y;
    int e;
    for (e = 0; e < E_NUM; e++) {
        int te = (cnt[e] + 127) >> 7;
        if (mt < te) break;
        mt -= te;
    }
    if (e >= E_NUM) return;
    int row0 = seg[e] + mt * 128;
    int col0 = blockIdx.x * 128;

    __shared__ unsigned short As[128 * 32];
    __shared__ unsigned short Bs[128 * 32];

    const unsigned short* Ab = Ag + (size_t)row0 * KDIM;
    const unsigned short* Bb = Bt + (size_t)e * NDIM * KDIM + (size_t)col0 * KDIM;

    int tid = threadIdx.x;
    int lane = tid & 63;
    int wv = tid >> 6;
    int wr = (wv >> 1) * 64, wc = (wv & 1) * 64;

    f32x4 acc[4][4] = {};

    int srow = lane >> 2;          // 0..15: row within 16-row chunk
    int scol = (lane & 3) * 8;     // 0/8/16/24: element offset (16B)

    for (int kk = 0; kk < KDIM; kk += 32) {
#pragma unroll
        for (int r = 0; r < 2; r++) {
            int chunk = wv + 4 * r;            // 0..7, 16 rows each
            int rowa = 16 * chunk + srow;
            load_lds16(Ab + (size_t)rowa * KDIM + kk + scol, &As[16 * chunk * 32]);
            load_lds16(Bb + (size_t)rowa * KDIM + kk + scol, &Bs[16 * chunk * 32]);
        }
        __syncthreads();           // drains vmcnt (global_load_lds) + barrier
        bf16x8 af[4], bfr[4];
        int fr = lane & 15, fq = (lane >> 4) * 8;
#pragma unroll
        for (int i = 0; i < 4; i++) {
            af[i]  = *(const bf16x8*)&As[(wr + i * 16 + fr) * 32 + fq];
            bfr[i] = *(const bf16x8*)&Bs[(wc + i * 16 + fr) * 32 + fq];
        }
#pragma unroll
        for (int i = 0; i < 4; i++)
#pragma unroll
            for (int j = 0; j < 4; j++)
                acc[i][j] = __builtin_amdgcn_mfma_f32_16x16x32_bf16(af[i], bfr[j], acc[i][j], 0, 0, 0);
        __syncthreads();
    }

    // epilogue; C/D layout: col = lane&15, row = (lane>>4)*4 + reg
    int cl = lane & 15, rq = (lane >> 4) * 4;
#pragma unroll
    for (int i = 0; i < 4; i++) {
#pragma unroll
        for (int j = 0; j < 4; j++) {
            int gcol = col0 + wc + j * 16 + cl;
            float b = bias[e * NDIM + gcol];
#pragma unroll
            for (int r = 0; r < 4; r++) {
                int grow = row0 + wr + i * 16 + rq + r;
                float v = acc[i][j][r] + b;
                if (EPI == 1) {
                    v = 0.5f * v * (1.0f + erff(v * 0.70710678118654752f));  // exact gelu
                    hg[(size_t)grow * NDIM + gcol] = f2bf(v);
                } else {
                    int token = inv_row[grow];
                    if (token >= 0) out[(size_t)token * NDIM + gcol] = rowprob[grow] * v;
                }
            }
        }
    }
}

// ---------------------------------------------------------------------------
extern "C" void kernel_launch(void* const* d_in, const int* in_sizes, int n_in,
                              void* d_out, int out_size, void* d_ws, size_t ws_size,
                              hipStream_t stream) {
    const float* x  = (const float*)d_in[0];
    const float* Wr = (const float*)d_in[1];
    const float* br = (const float*)d_in[2];
    const float* W1 = (const float*)d_in[3];
    const float* b1 = (const float*)d_in[4];
    const float* W2 = (const float*)d_in[5];
    const float* b2 = (const float*)d_in[6];
    float* out = (float*)d_out;

    // workspace layout (~218.3 MB)
    char* ws = (char*)d_ws;
    unsigned short* W1t = (unsigned short*)ws;                               // [E][H][C] bf16, 64MB
    unsigned short* W2t = (unsigned short*)(ws + (64ull << 20));             // [E][C][H] bf16, 64MB
    unsigned short* xg  = (unsigned short*)(ws + (128ull << 20));            // [ROWS_PAD][C] bf16, 18MB
    unsigned short* hg  = (unsigned short*)(ws + (128ull << 20) + 18874368ull); // [ROWS_PAD][H] bf16, 72MB
    char* small = ws + (128ull << 20) + 18874368ull + 75497472ull;
    float* probs   = (float*)small;                    // 32KB
    int*   eidx    = (int*)(small + 32768);            // 32KB
    float* rowprob = (float*)(small + 65536);          // 36KB
    int*   inv_row = (int*)(small + 65536 + 36864);    // 36KB
    int*   cnt     = (int*)(small + 65536 + 73728);    // 8
    int*   fill    = cnt + 8;                          // 8
    int*   seg     = cnt + 16;                         // 8

    hipMemsetAsync(cnt, 0, 64, stream);                                   // cnt+fill
    hipMemsetAsync(xg, 0, (size_t)ROWS_PAD * C_DIM * 2, stream);          // zero pads
    hipMemsetAsync(inv_row, 0xFF, ROWS_PAD * 4, stream);                  // -1

    // W1 [E][C][H] -> W1t [E][H][C] ; W2 [E][H][C] -> W2t [E][C][H]
    transpose_w<<<dim3(H_DIM / 64, C_DIM / 256, E_NUM), 256, 0, stream>>>(W1, W1t, C_DIM, H_DIM);
    transpose_w<<<dim3(C_DIM / 64, H_DIM / 256, E_NUM), 256, 0, stream>>>(W2, W2t, H_DIM, C_DIM);

    router_kernel<<<N_TOK / 4, 256, 0, stream>>>(x, Wr, br, probs, eidx, cnt);
    finalize_kernel<<<1, 64, 0, stream>>>(cnt, seg, out + (size_t)N_TOK * C_DIM);
    gather_kernel<<<N_TOK / 4, 256, 0, stream>>>(x, probs, eidx, seg, fill, xg, inv_row, rowprob);

    // GEMM1: h = gelu(xg @ W1[e] + b1[e])   [rows x H], K=C
    moe_gemm<C_DIM, H_DIM, 1><<<dim3(H_DIM / 128, 72), 256, 0, stream>>>(
        xg, W1t, b1, hg, nullptr, cnt, seg, inv_row, rowprob);
    // GEMM2: out[token] = prob * (hg @ W2[e] + b2[e])   [rows x C], K=H
    moe_gemm<H_DIM, C_DIM, 2><<<dim3(C_DIM / 128, 72), 256, 0, stream>>>(
        hg, W2t, b2, nullptr, out, cnt, seg, inv_row, rowprob);
}

// Round 2
// 743.777 us; speedup vs baseline: 1.5313x; 1.5313x over previous
//
#include <hip/hip_runtime.h>
#include <hip/hip_bf16.h>
#include <stdint.h>

// Problem constants (from reference): B=4, T=2048 -> N=8192 tokens
#define N_TOK 8192
#define C_DIM 1024
#define E_NUM 8
#define H_DIM 4096
#define ROWS_PAD 9216   // 8192 + 8*128 upper bound on per-expert 128-padded rows
#define HBLK 32         // blocks in histogram/scan phase (256 tokens each)

typedef __attribute__((ext_vector_type(8))) short bf16x8;
typedef __attribute__((ext_vector_type(4))) float f32x4;

// round-to-nearest-even fp32 -> bf16
static __device__ __forceinline__ unsigned short f2bf(float f) {
    union { float f; unsigned u; } v; v.f = f;
    unsigned r = (v.u + 0x7FFFu + ((v.u >> 16) & 1u)) >> 16;
    return (unsigned short)r;
}

// async global->LDS, 16B per lane (LDS dest = wave-uniform base + lane*16)
static __device__ __forceinline__ void load_lds16(const unsigned short* g, unsigned short* l) {
    __builtin_amdgcn_global_load_lds(
        (const __attribute__((address_space(1))) unsigned int*)g,
        (__attribute__((address_space(3))) unsigned int*)l, 16, 0, 0);
}

// ---------------------------------------------------------------------------
// Transpose + cast: in [E][K][N] fp32  ->  out [E][N][K] bf16
// ---------------------------------------------------------------------------
__global__ void transpose_w(const float* __restrict__ in, unsigned short* __restrict__ out,
                            int K, int N) {
    int e  = blockIdx.z;
    int n0 = blockIdx.x * 64;
    int k0 = blockIdx.y * 256;
    int t = threadIdx.x;
    int lane = t & 63;
    int w = t >> 6;
    const float* ip = in + (size_t)e * K * N;
    unsigned short* op = out + (size_t)e * N * K;
    int n = n0 + lane;
    for (int kb = k0 + w * 8; kb < k0 + 256; kb += 32) {
        float v[8];
#pragma unroll
        for (int j = 0; j < 8; j++) v[j] = ip[(size_t)(kb + j) * N + n];
        uint4 pk;
        pk.x = (unsigned)f2bf(v[0]) | ((unsigned)f2bf(v[1]) << 16);
        pk.y = (unsigned)f2bf(v[2]) | ((unsigned)f2bf(v[3]) << 16);
        pk.z = (unsigned)f2bf(v[4]) | ((unsigned)f2bf(v[5]) << 16);
        pk.w = (unsigned)f2bf(v[6]) | ((unsigned)f2bf(v[7]) << 16);
        *(uint4*)&op[(size_t)n * K + kb] = pk;
    }
}

// ---------------------------------------------------------------------------
// Router: one wave per token, fp64 accumulation. NO global atomics.
// ---------------------------------------------------------------------------
__global__ void router_kernel(const float* __restrict__ x, const float* __restrict__ Wr,
                              const float* __restrict__ br,
                              float* __restrict__ probs, int* __restrict__ eidx) {
    int n = blockIdx.x * 4 + (threadIdx.x >> 6);
    int lane = threadIdx.x & 63;
    const float* xr = x + (size_t)n * C_DIM;
    double acc[E_NUM];
#pragma unroll
    for (int e = 0; e < E_NUM; e++) acc[e] = 0.0;
    for (int i = 0; i < 16; i++) {
        int c = i * 64 + lane;
        float xv = xr[c];
        const float4* wr = (const float4*)(Wr + c * E_NUM);
        float4 w0 = wr[0], w1 = wr[1];
        acc[0] += (double)xv * w0.x; acc[1] += (double)xv * w0.y;
        acc[2] += (double)xv * w0.z; acc[3] += (double)xv * w0.w;
        acc[4] += (double)xv * w1.x; acc[5] += (double)xv * w1.y;
        acc[6] += (double)xv * w1.z; acc[7] += (double)xv * w1.w;
    }
#pragma unroll
    for (int e = 0; e < E_NUM; e++) {
#pragma unroll
        for (int o = 32; o > 0; o >>= 1) acc[e] += __shfl_xor(acc[e], o, 64);
    }
    if (lane == 0) {
        float l[E_NUM];
        for (int e = 0; e < E_NUM; e++) l[e] = (float)acc[e] + br[e];
        int arg = 0; float m = l[0];
        for (int e = 1; e < E_NUM; e++) if (l[e] > m) { m = l[e]; arg = e; }  // first-max
        float s = 0.f;
        for (int e = 0; e < E_NUM; e++) s += expf(l[e] - m);
        probs[n] = 1.0f / s;     // = exp(lmax-m)/sum
        eidx[n] = arg;
    }
}

// ---------------------------------------------------------------------------
// Phase 1: per-block expert histogram (LDS atomics only)
// ---------------------------------------------------------------------------
__global__ void hist_kernel(const int* __restrict__ eidx, int* __restrict__ blk_cnt) {
    __shared__ int lh[E_NUM];
    int t = threadIdx.x, b = blockIdx.x;
    if (t < E_NUM) lh[t] = 0;
    __syncthreads();
    atomicAdd(&lh[eidx[b * 256 + t]], 1);
    __syncthreads();
    if (t < E_NUM) blk_cnt[b * E_NUM + t] = lh[t];
}

// ---------------------------------------------------------------------------
// Finalize: totals, 128-padded segment offsets, per-block bases, aux loss
// ---------------------------------------------------------------------------
__global__ void finalize_kernel(const int* __restrict__ blk_cnt, int* __restrict__ cnt,
                                int* __restrict__ seg, int* __restrict__ blockbase,
                                float* __restrict__ aux_out) {
    if (threadIdx.x == 0) {
        int tot[E_NUM];
        for (int e = 0; e < E_NUM; e++) tot[e] = 0;
        for (int b = 0; b < HBLK; b++)
            for (int e = 0; e < E_NUM; e++) tot[e] += blk_cnt[b * E_NUM + e];
        int off = 0;
        for (int e = 0; e < E_NUM; e++) {
            cnt[e] = tot[e];
            seg[e] = off;
            off += ((tot[e] + 127) >> 7) << 7;
        }
        int run[E_NUM];
        for (int e = 0; e < E_NUM; e++) run[e] = seg[e];
        for (int b = 0; b < HBLK; b++)
            for (int e = 0; e < E_NUM; e++) {
                blockbase[b * E_NUM + e] = run[e];
                run[e] += blk_cnt[b * E_NUM + e];
            }
        float s = 0.f;
        for (int e = 0; e < E_NUM; e++) {
            float fr = (float)tot[e] / (float)N_TOK - 1.0f / E_NUM;
            s += fr * fr;
        }
        aux_out[0] = s / (float)E_NUM;
    }
}

// ---------------------------------------------------------------------------
// Phase 2: assign rows (LDS-atomic local rank + precomputed block base)
// ---------------------------------------------------------------------------
__global__ void gatherpos_kernel(const float* __restrict__ probs, const int* __restrict__ eidx,
                                 const int* __restrict__ blockbase, int* __restrict__ tok_row,
                                 int* __restrict__ inv_row, float* __restrict__ rowprob) {
    __shared__ int lh[E_NUM];
    int t = threadIdx.x, b = blockIdx.x;
    if (t < E_NUM) lh[t] = 0;
    __syncthreads();
    int n = b * 256 + t;
    int e = eidx[n];
    int lrank = atomicAdd(&lh[e], 1);
    int row = blockbase[b * E_NUM + e] + lrank;
    tok_row[n] = row;
    inv_row[row] = n;
    rowprob[row] = probs[n];
}

// ---------------------------------------------------------------------------
// Copy: cast x rows into expert-grouped bf16 buffer; one wave per token
// ---------------------------------------------------------------------------
__global__ void copy_kernel(const float* __restrict__ x, const int* __restrict__ tok_row,
                            unsigned short* __restrict__ xg) {
    int n = blockIdx.x * 4 + (threadIdx.x >> 6);
    int lane = threadIdx.x & 63;
    int row = tok_row[n];
    const float2* xr = (const float2*)(x + (size_t)n * C_DIM);
    unsigned* xgr = (unsigned*)(xg + (size_t)row * C_DIM);
#pragma unroll
    for (int i = 0; i < 8; i++) {
        float2 v = xr[i * 64 + lane];
        xgr[i * 64 + lane] = (unsigned)f2bf(v.x) | ((unsigned)f2bf(v.y) << 16);
    }
}

// ---------------------------------------------------------------------------
// Grouped GEMM, m97 structure: 128x128 tile, BK=32, 256 thr (4 waves, each
// 64x64 = 4x4 MFMA 16x16x32 tiles). A [rows,K] bf16 k-contig, Bt [E][N][K]
// bf16 k-contig. EPI=1: +bias, exact gelu, bf16 store to hg.
// EPI=2: +bias, *gate, scatter fp32 to out by inv_row.
// ---------------------------------------------------------------------------
template <int KDIM, int NDIM, int EPI>
__global__ __launch_bounds__(256) void moe_gemm(
    const unsigned short* __restrict__ Ag, const unsigned short* __restrict__ Bt,
    const float* __restrict__ bias, unsigned short* __restrict__ hg,
    float* __restrict__ out, const int* __restrict__ cnt, const int* __restrict__ seg,
    const int* __restrict__ inv_row, const float* __restrict__ rowprob) {
    // map m-slot -> (expert, m-tile)
    int mt = blockIdx.y;
    int e;
    for (e = 0; e < E_NUM; e++) {
        int te = (cnt[e] + 127) >> 7;
        if (mt < te) break;
        mt -= te;
    }
    if (e >= E_NUM) return;
    int row0 = seg[e] + mt * 128;
    int col0 = blockIdx.x * 128;

    __shared__ unsigned short As[128 * 32];
    __shared__ unsigned short Bs[128 * 32];

    const unsigned short* Ab = Ag + (size_t)row0 * KDIM;
    const unsigned short* Bb = Bt + (size_t)e * NDIM * KDIM + (size_t)col0 * KDIM;

    int tid = threadIdx.x;
    int lane = tid & 63;
    int wv = tid >> 6;
    int wr = (wv >> 1) * 64, wc = (wv & 1) * 64;

    f32x4 acc[4][4] = {};

    int srow = lane >> 2;          // 0..15: row within 16-row chunk
    int scol = (lane & 3) * 8;     // 0/8/16/24: element offset (16B)

    for (int kk = 0; kk < KDIM; kk += 32) {
#pragma unroll
        for (int r = 0; r < 2; r++) {
            int chunk = wv + 4 * r;            // 0..7, 16 rows each
            int rowa = 16 * chunk + srow;
            load_lds16(Ab + (size_t)rowa * KDIM + kk + scol, &As[16 * chunk * 32]);
            load_lds16(Bb + (size_t)rowa * KDIM + kk + scol, &Bs[16 * chunk * 32]);
        }
        __syncthreads();           // drains vmcnt (global_load_lds) + barrier
        bf16x8 af[4], bfr[4];
        int fr = lane & 15, fq = (lane >> 4) * 8;
#pragma unroll
        for (int i = 0; i < 4; i++) {
            af[i]  = *(const bf16x8*)&As[(wr + i * 16 + fr) * 32 + fq];
            bfr[i] = *(const bf16x8*)&Bs[(wc + i * 16 + fr) * 32 + fq];
        }
#pragma unroll
        for (int i = 0; i < 4; i++)
#pragma unroll
            for (int j = 0; j < 4; j++)
                acc[i][j] = __builtin_amdgcn_mfma_f32_16x16x32_bf16(af[i], bfr[j], acc[i][j], 0, 0, 0);
        __syncthreads();
    }

    // epilogue; C/D layout: col = lane&15, row = (lane>>4)*4 + reg
    int cl = lane & 15, rq = (lane >> 4) * 4;
#pragma unroll
    for (int i = 0; i < 4; i++) {
#pragma unroll
        for (int j = 0; j < 4; j++) {
            int gcol = col0 + wc + j * 16 + cl;
            float b = bias[e * NDIM + gcol];
#pragma unroll
            for (int r = 0; r < 4; r++) {
                int grow = row0 + wr + i * 16 + rq + r;
                float v = acc[i][j][r] + b;
                if (EPI == 1) {
                    v = 0.5f * v * (1.0f + erff(v * 0.70710678118654752f));  // exact gelu
                    hg[(size_t)grow * NDIM + gcol] = f2bf(v);
                } else {
                    int token = inv_row[grow];
                    if (token >= 0) out[(size_t)token * NDIM + gcol] = rowprob[grow] * v;
                }
            }
        }
    }
}

// ---------------------------------------------------------------------------
extern "C" void kernel_launch(void* const* d_in, const int* in_sizes, int n_in,
                              void* d_out, int out_size, void* d_ws, size_t ws_size,
                              hipStream_t stream) {
    const float* x  = (const float*)d_in[0];
    const float* Wr = (const float*)d_in[1];
    const float* br = (const float*)d_in[2];
    const float* W1 = (const float*)d_in[3];
    const float* b1 = (const float*)d_in[4];
    const float* W2 = (const float*)d_in[5];
    const float* b2 = (const float*)d_in[6];
    float* out = (float*)d_out;

    // workspace layout (~218.4 MB)
    char* ws = (char*)d_ws;
    unsigned short* W1t = (unsigned short*)ws;                               // [E][H][C] bf16, 64MB
    unsigned short* W2t = (unsigned short*)(ws + (64ull << 20));             // [E][C][H] bf16, 64MB
    unsigned short* xg  = (unsigned short*)(ws + (128ull << 20));            // [ROWS_PAD][C] bf16, 18MB
    unsigned short* hg  = (unsigned short*)(ws + (128ull << 20) + 18874368ull); // [ROWS_PAD][H] bf16, 72MB
    char* small = ws + (128ull << 20) + 18874368ull + 75497472ull;
    float* probs     = (float*)small;                       // 32KB
    int*   eidx      = (int*)(small + 32768);               // 32KB
    float* rowprob   = (float*)(small + 65536);             // 36KB
    int*   inv_row   = (int*)(small + 65536 + 36864);       // 36KB
    int*   tok_row   = (int*)(small + 65536 + 73728);       // 32KB
    int*   blk_cnt   = (int*)(small + 65536 + 73728 + 32768);        // 1KB
    int*   blockbase = blk_cnt + HBLK * E_NUM;                       // 1KB
    int*   cnt       = blockbase + HBLK * E_NUM;                     // 8
    int*   seg       = cnt + 8;                                      // 8

    hipMemsetAsync(xg, 0, (size_t)ROWS_PAD * C_DIM * 2, stream);          // zero pads
    hipMemsetAsync(inv_row, 0xFF, ROWS_PAD * 4, stream);                  // -1

    // W1 [E][C][H] -> W1t [E][H][C] ; W2 [E][H][C] -> W2t [E][C][H]
    transpose_w<<<dim3(H_DIM / 64, C_DIM / 256, E_NUM), 256, 0, stream>>>(W1, W1t, C_DIM, H_DIM);
    transpose_w<<<dim3(C_DIM / 64, H_DIM / 256, E_NUM), 256, 0, stream>>>(W2, W2t, H_DIM, C_DIM);

    router_kernel<<<N_TOK / 4, 256, 0, stream>>>(x, Wr, br, probs, eidx);
    hist_kernel<<<HBLK, 256, 0, stream>>>(eidx, blk_cnt);
    finalize_kernel<<<1, 64, 0, stream>>>(blk_cnt, cnt, seg, blockbase,
                                          out + (size_t)N_TOK * C_DIM);
    gatherpos_kernel<<<HBLK, 256, 0, stream>>>(probs, eidx, blockbase, tok_row, inv_row, rowprob);
    copy_kernel<<<N_TOK / 4, 256, 0, stream>>>(x, tok_row, xg);

    // GEMM1: h = gelu(xg @ W1[e] + b1[e])   [rows x H], K=C
    moe_gemm<C_DIM, H_DIM, 1><<<dim3(H_DIM / 128, 72), 256, 0, stream>>>(
        xg, W1t, b1, hg, nullptr, cnt, seg, inv_row, rowprob);
    // GEMM2: out[token] = prob * (hg @ W2[e] + b2[e])   [rows x C], K=H
    moe_gemm<H_DIM, C_DIM, 2><<<dim3(C_DIM / 128, 72), 256, 0, stream>>>(
        hg, W2t, b2, nullptr, out, cnt, seg, inv_row, rowprob);
}